// Round 1
// 514.344 us; speedup vs baseline: 1.3350x; 1.3350x over previous
//
#include <hip/hip_runtime.h>

// ---------------------------------------------------------------------------
// O3onO2 tensor product, LS=[0,1,2,3], MULS=64 each, N=65536, DIM=1024.
// Formulation: out = x @ M^T where M is block-diagonal after grouping
// channels by m:  m=0: 256x256, m=1: 384x384, m=2: 256x256, m=3: 128x128.
// M_m[(ob_rel,so,o),(ib_rel,si,i)] = C[so][si] * W_p[o,i],  p = ob*4+ib,
//   C = [[hp, hn], [-hn, hp]]  (m>=1),  C = [[hzero]] (m=0).
//
// R1 change: epilogue now stages the 64x1024 output tile through LDS in
// four 16-row passes so global stores are coalesced float4 (was: per-lane
// scattered 4B stores -> 4.4x HBM write amplification, 1.13 GB written).
// ---------------------------------------------------------------------------

typedef __attribute__((ext_vector_type(8))) short bhalf8_t;   // 8 x bf16 bits
typedef __attribute__((ext_vector_type(4))) float f32x4_t;

#define NROWS 65536
#define DIMV  1024

// M_m element offsets in workspace (bf16 elements)
#define M0_OFF 0
#define M1_OFF 65536
#define M2_OFF 212992
#define M3_OFF 278528
#define M_TOTAL 294912

// Epilogue LDS tile: 16 rows x 1024 cols fp32, padded row stride.
// OP=1028 words: row*1028 ≡ 4*row (mod 32) banks; odd-stride col scatter
// within a 16-lane group covers distinct banks -> <=2-way conflicts.
#define OP 1028

__device__ __forceinline__ short f2bf(float f) {
    unsigned u = __builtin_bit_cast(unsigned, f);
    u = (u + 0x7FFFu + ((u >> 16) & 1u)) >> 16;   // round-to-nearest-even
    return (short)u;
}

// ---------------------------------------------------------------------------
// Kernel 1: build block-diagonal group matrices M_m (bf16) into workspace.
// ---------------------------------------------------------------------------
__global__ __launch_bounds__(256) void build_M(const float* __restrict__ w,
                                               const float* __restrict__ hz,
                                               const float* __restrict__ hp,
                                               const float* __restrict__ hn,
                                               short* __restrict__ M) {
    int idx = blockIdx.x * 256 + threadIdx.x;
    if (idx >= M_TOTAL) return;

    int m, A, B;
    if (idx < M1_OFF)      { m = 0; int lo = idx;            A = lo / 256u; B = lo - A * 256; }
    else if (idx < M2_OFF) { m = 1; int lo = idx - M1_OFF;   A = lo / 384u; B = lo - A * 384; }
    else if (idx < M3_OFF) { m = 2; int lo = idx - M2_OFF;   A = lo / 256u; B = lo - A * 256; }
    else                   { m = 3; int lo = idx - M3_OFF;   A = lo / 128u; B = lo - A * 128; }

    int ob, so, o, ib, si, i;
    if (m == 0) { ob = A >> 6;       so = 0;            o = A & 63;
                  ib = B >> 6;       si = 0;            i = B & 63; }
    else        { ob = (A >> 7) + m; so = (A >> 6) & 1; o = A & 63;
                  ib = (B >> 7) + m; si = (B >> 6) & 1; i = B & 63; }

    int p = ob * 4 + ib;
    float wv = w[p * 4096 + o * 64 + i];
    float coef;
    if (m == 0) {
        coef = hz[p];
    } else {
        float hpv = hp[p * 3 + (m - 1)];
        float hnv = hn[p * 3 + (m - 1)];
        coef = (so == 0) ? ((si == 0) ? hpv : hnv)
                         : ((si == 0) ? -hnv : hpv);
    }
    M[idx] = f2bf(wv * coef);
}

// ---------------------------------------------------------------------------
// Kernel 2: main. One WG = 64 rows x all 1024 out cols. 1024 threads (16
// waves). Waves 0-3: m=0 (256 cols), 4-9: m=1 (384), 10-13: m=2 (256),
// 14-15: m=3 (128). Each wave: 4 col-tiles x 4 row-tiles of 16x16 MFMA.
// ---------------------------------------------------------------------------
__global__ __launch_bounds__(1024) void tp_main(const float* __restrict__ x,
                                                const short* __restrict__ Mall,
                                                float* __restrict__ out) {
    // Shared pool, reused:
    //  phase A (compute): x-tile, channel-major per block: [row][ji*72 + i],
    //    bf16. Max block l=3: 64 rows * 7*72 el * 2B = 64512 B.
    //  phase B (epilogue): 16 x OP fp32 output staging = 65792 B.
    __shared__ __align__(16) char smem[16 * OP * 4];
    short* __restrict__ xbuf = (short*)smem;
    float* __restrict__ obuf = (float*)smem;

    const int tid  = threadIdx.x;
    const int lane = tid & 63;
    const int lr   = lane & 15;       // MFMA row/col lane index
    const int q    = lane >> 4;       // quad
    const int wv   = tid >> 6;        // wave id 0..15
    const int rowbase = blockIdx.x << 6;

    int m, cb;
    if (wv < 4)       { m = 0; cb = wv << 6; }
    else if (wv < 10) { m = 1; cb = (wv - 4) << 6; }
    else if (wv < 14) { m = 2; cb = (wv - 10) << 6; }
    else              { m = 3; cb = (wv - 14) << 6; }
    const int Wm   = (m == 1) ? 384 : ((m == 3) ? 128 : 256);
    const int Moff = (m == 0) ? M0_OFF : (m == 1) ? M1_OFF : (m == 2) ? M2_OFF : M3_OFF;
    const short* __restrict__ Mg = Mall + Moff;

    f32x4_t acc[4][4];   // [col-tile][row-tile]
#pragma unroll
    for (int c = 0; c < 4; ++c)
#pragma unroll
        for (int r = 0; r < 4; ++r)
            acc[c][r] = (f32x4_t){0.f, 0.f, 0.f, 0.f};

#pragma unroll
    for (int ii = 0; ii < 4; ++ii) {
        const int l   = ii;
        const int nch = 2 * l + 1;
        const int d4  = 16 * nch;       // float4-chunks per row in this block
        const int RS  = nch * 72;       // LDS row stride (elements)
        const int bo  = 64 * l * l;     // block col offset in x: 0,64,256,576

        __syncthreads();                // protect xbuf readers of prev block

        // ---- stage: global fp32 (coalesced) -> bf16 -> LDS channel-major
#pragma unroll
        for (int e = 0; e < nch; ++e) { // exactly nch full passes of 1024 thr
            int id  = e * 1024 + tid;
            int row = id / d4;
            int cc  = id - row * d4;
            int col = cc * 4;
            const float4 v = *(const float4*)(x + (size_t)(rowbase + row) * DIMV + bo + col);
            short* dst = &xbuf[row * RS];
            { int ci = col;     int i = ci / nch; int ji = ci - i * nch; dst[ji * 72 + i] = f2bf(v.x); }
            { int ci = col + 1; int i = ci / nch; int ji = ci - i * nch; dst[ji * 72 + i] = f2bf(v.y); }
            { int ci = col + 2; int i = ci / nch; int ji = ci - i * nch; dst[ji * 72 + i] = f2bf(v.z); }
            { int ci = col + 3; int i = ci / nch; int ji = ci - i * nch; dst[ji * 72 + i] = f2bf(v.w); }
        }
        __syncthreads();

        // ---- compute: this block feeds groups m <= l
        if (m <= l) {
            const int nsi = (m == 0) ? 1 : 2;
            for (int si = 0; si < nsi; ++si) {
                const int ji    = l + ((si == 0) ? m : -m);
                const int kbase = ((m == 0) ? (ii << 6) : (((ii - m) << 7) + (si << 6)));
#pragma unroll
                for (int kk = 0; kk < 2; ++kk) {
                    bhalf8_t a[4];
                    const int eo = ji * 72 + kk * 32 + q * 8;
#pragma unroll
                    for (int r = 0; r < 4; ++r)
                        a[r] = *(const bhalf8_t*)&xbuf[(r * 16 + lr) * RS + eo];
                    const int ko = kbase + kk * 32 + q * 8;
#pragma unroll
                    for (int c = 0; c < 4; ++c) {
                        const bhalf8_t b = *(const bhalf8_t*)&Mg[(cb + c * 16 + lr) * Wm + ko];
#pragma unroll
                        for (int r = 0; r < 4; ++r)
                            acc[c][r] = __builtin_amdgcn_mfma_f32_16x16x32_bf16(
                                a[r], b, acc[c][r], 0, 0, 0);
                    }
                }
            }
        }
    }

    // ---- epilogue: un-permute columns via LDS, drain with coalesced float4.
    // C/D layout: col = lane&15, row = (lane>>4)*4 + reg   [m89-verified]
    // Per-wave column -> original column (loop-invariant over row passes):
    int origc[4];
#pragma unroll
    for (int c = 0; c < 4; ++c) {
        const int P = cb + c * 16 + lr;
        int ob, o, jo;
        if (m == 0) { ob = P >> 6;       o = P & 63; jo = ob; }
        else        { ob = (P >> 7) + m; o = P & 63;
                      jo = ob + ((((P >> 6) & 1) == 0) ? m : -m); }
        origc[c] = 64 * ob * ob + o * (2 * ob + 1) + jo;
    }

#pragma unroll
    for (int r = 0; r < 4; ++r) {
        __syncthreads();               // xbuf/obuf readers of prev phase done
        // scatter this 16-row slice into LDS (4B LDS writes, odd strides)
#pragma unroll
        for (int c = 0; c < 4; ++c) {
#pragma unroll
            for (int g = 0; g < 4; ++g)
                obuf[(q * 4 + g) * OP + origc[c]] = acc[c][r][g];
        }
        __syncthreads();
        // drain: 16 rows x 1024 cols = 4096 float4, 4 per thread, coalesced
#pragma unroll
        for (int it = 0; it < 4; ++it) {
            const int j   = it * 1024 + tid;
            const int row = j >> 8;
            const int c4  = (j & 255) << 2;
            const float4 v = *(const float4*)&obuf[row * OP + c4];
            *(float4*)&out[(size_t)(rowbase + r * 16 + row) * DIMV + c4] = v;
        }
    }
}

// ---------------------------------------------------------------------------
extern "C" void kernel_launch(void* const* d_in, const int* in_sizes, int n_in,
                              void* d_out, int out_size, void* d_ws, size_t ws_size,
                              hipStream_t stream) {
    const float* x   = (const float*)d_in[0];
    const float* wts = (const float*)d_in[1];
    const float* hz  = (const float*)d_in[2];
    const float* hp  = (const float*)d_in[3];
    const float* hn  = (const float*)d_in[4];
    float* out = (float*)d_out;
    short* M   = (short*)d_ws;   // needs 294912 * 2 = 589824 bytes

    build_M<<<dim3(M_TOTAL / 256), dim3(256), 0, stream>>>(wts, hz, hp, hn, M);
    tp_main<<<dim3(NROWS / 64), dim3(1024), 0, stream>>>(x, M, out);
}